// Round 3
// baseline (220.925 us; speedup 1.0000x reference)
//
#include <hip/hip_runtime.h>

#define NT 512   // trajectories
#define PD 256   // dimension

__device__ __forceinline__ float wave_reduce_sum(float v) {
    #pragma unroll
    for (int m = 32; m >= 1; m >>= 1) v += __shfl_xor(v, m, 64);
    return v;
}

// One 1024-thread block per trajectory (16 waves).
// Phase 1: wave-per-row dual matvec vs predicted_mat (coalesced float4 row
// loads, butterfly shuffle reduce) -> sQ/sG in LDS. 16 rows per wave.
// Phase 2 (threads 0..255): tiny-MLP epilogue + rank-2 BFGS update applied
// directly to v = -grad (new_mat never materialized).
// LDS ~4.2 KB, VGPR <=128 (launch_bounds) => 16 waves/CU resident.
__global__ __launch_bounds__(1024, 4) void fused_kernel(
    const float* __restrict__ pm, const float* __restrict__ grad,
    const float* __restrict__ gradm1, const float* __restrict__ dm1,
    const float* __restrict__ Wfs, const float* __restrict__ Wo1,
    const float* __restrict__ Wo2, const float* __restrict__ Wo3,
    const float* __restrict__ Wl1, const float* __restrict__ Wl2,
    const float* __restrict__ Wl3, float* __restrict__ dout)
{
    __shared__ float sQ[PD];
    __shared__ float sG[PD];
    __shared__ float sW[516];
    __shared__ float redA[4][3];
    __shared__ float redB[4][4];

    const int t    = threadIdx.x;
    const int lane = t & 63;
    const int wave = t >> 6;    // 0..15
    const int n    = blockIdx.x;

    // ---- stage tiny weights (covered by the barrier after phase 1) ----
    // layout: Wo1@0(18) Wo2@18(72) Wo3@90(36) Wl1@126(72) Wl2@198(288)
    //         Wl3@486(24) Wfs@510(6)
    if (t < 18)  sW[t]       = Wo1[t];
    if (t < 72)  sW[18 + t]  = Wo2[t];
    if (t < 36)  sW[90 + t]  = Wo3[t];
    if (t < 72)  sW[126 + t] = Wl1[t];
    if (t < 288) sW[198 + t] = Wl2[t];
    if (t < 24)  sW[486 + t] = Wl3[t];
    if (t < 6)   sW[510 + t] = Wfs[t];

    // ---- phase 1: dual matvec, wave-per-row ----
    const float4 g4  = ((const float4*)(grad   + n * PD))[lane];
    const float4 gm4 = ((const float4*)(gradm1 + n * PD))[lane];
    const float4 dg4 = make_float4(g4.x - gm4.x, g4.y - gm4.y,
                                   g4.z - gm4.z, g4.w - gm4.w);

    const float* base = pm + (size_t)n * PD * PD;
    const int row0 = wave * 16;
    #pragma unroll 4
    for (int r = 0; r < 16; ++r) {
        const int row = row0 + r;
        const float4 m4 = ((const float4*)(base + (size_t)row * PD))[lane];
        float aq = m4.x * dg4.x + m4.y * dg4.y + m4.z * dg4.z + m4.w * dg4.w;
        float ag = m4.x * g4.x  + m4.y * g4.y  + m4.z * g4.z  + m4.w * g4.w;
        aq = wave_reduce_sum(aq);
        ag = wave_reduce_sum(ag);
        if (lane == 0) { sQ[row] = aq; sG[row] = ag; }
    }
    __syncthreads();

    // ---- phase 2: epilogue on threads 0..255 (waves 0..3) ----
    float q = 0.f, bg = 0.f, g = 0.f, gm = 0.f, dm = 0.f;
    float x0 = 0.f, x1 = 0.f, x2 = 0.f;
    float o0 = 0.f, o1 = 0.f, o2 = 0.f;

    if (t < PD) {
        const int idx = n * PD + t;
        q  = sQ[t];
        bg = -sG[t];          // Bg = -pm@grad = pm@v
        g  = grad[idx];
        gm = gradm1[idx];
        dm = dm1[idx];

        x0 = q; x1 = dm; x2 = bg;

        // outer_FF: 3 -> 6 -> 12 -> 3
        float h1[6];
        #pragma unroll
        for (int j = 0; j < 6; ++j) {
            float s = sW[j*3] * x0 + sW[j*3 + 1] * x1 + sW[j*3 + 2] * x2;
            h1[j] = fmaxf(s, 0.f);
        }
        float h2[12];
        #pragma unroll
        for (int j = 0; j < 12; ++j) {
            float s = 0.f;
            #pragma unroll
            for (int i = 0; i < 6; ++i) s += sW[18 + j*6 + i] * h1[i];
            h2[j] = fmaxf(s, 0.f);
        }
        #pragma unroll
        for (int i = 0; i < 12; ++i) {
            o0 += sW[90 + i]      * h2[i];
            o1 += sW[90 + 12 + i] * h2[i];
            o2 += sW[90 + 24 + i] * h2[i];
        }
        // mean over P: stage 1 (whole waves 0..3 active => shuffles safe)
        float r0 = wave_reduce_sum(o0);
        float r1 = wave_reduce_sum(o1);
        float r2 = wave_reduce_sum(o2);
        if (lane == 0) { redA[wave][0] = r0; redA[wave][1] = r1; redA[wave][2] = r2; }
    }
    __syncthreads();

    float out = 0.f, secant = 0.f, dgk = 0.f;
    if (t < PD) {
        const float inv = 1.0f / 256.0f;
        const float of0 = (redA[0][0] + redA[1][0] + redA[2][0] + redA[3][0]) * inv;
        const float of1 = (redA[0][1] + redA[1][1] + redA[2][1] + redA[3][1]) * inv;
        const float of2 = (redA[0][2] + redA[1][2] + redA[2][2] + redA[3][2]) * inv;

        const float x6[6] = {x0, x1, x2, of0, of1, of2};

        float fullskip = 0.f;
        #pragma unroll
        for (int i = 0; i < 6; ++i) fullskip += sW[510 + i] * x6[i];

        // inner MLP: 6 -> 12 -> 24 -> 1
        float l1[12];
        #pragma unroll
        for (int j = 0; j < 12; ++j) {
            float s = 0.f;
            #pragma unroll
            for (int i = 0; i < 6; ++i) s += sW[126 + j*6 + i] * x6[i];
            l1[j] = fmaxf(s, 0.f);
        }
        float l2[24];
        #pragma unroll
        for (int j = 0; j < 24; ++j) {
            float s = 0.f;
            #pragma unroll
            for (int i = 0; i < 12; ++i) s += sW[198 + j*12 + i] * l1[i];
            l2[j] = fmaxf(s, 0.f);
        }
        out = fullskip;
        #pragma unroll
        for (int i = 0; i < 24; ++i) out += sW[486 + i] * l2[i];

        dgk    = g - gm;
        secant = dm - q;

        float pd  = wave_reduce_sum(out * dgk);
        float ps  = wave_reduce_sum(secant * dgk);
        float po  = wave_reduce_sum(out * g);
        float psg = wave_reduce_sum(secant * g);
        if (lane == 0) {
            redB[wave][0] = pd; redB[wave][1] = ps;
            redB[wave][2] = po; redB[wave][3] = psg;
        }
    }
    __syncthreads();

    if (t < PD) {
        const float denom = redB[0][0] + redB[1][0] + redB[2][0] + redB[3][0];
        const float sdgk  = redB[0][1] + redB[1][1] + redB[2][1] + redB[3][1];
        const float og    = redB[0][2] + redB[1][2] + redB[2][2] + redB[3][2];
        const float sg2   = redB[0][3] + redB[1][3] + redB[2][3] + redB[3][3];

        // d = Bg + (1/denom)*( secant*(out.v) + out*(secant.v) - coef*out*(out.v) )
        // v = -grad => out.v = -og, secant.v = -sg2, coef = sdgk/denom
        const float invd = 1.0f / denom;
        const float coef = sdgk * invd;
        const float d = bg + (-secant * og - out * sg2 + coef * out * og) * invd;
        dout[n * PD + t] = d;
    }
}

extern "C" void kernel_launch(void* const* d_in, const int* in_sizes, int n_in,
                              void* d_out, int out_size, void* d_ws, size_t ws_size,
                              hipStream_t stream) {
    const float* grad   = (const float*)d_in[0];
    const float* gradm1 = (const float*)d_in[1];
    const float* dm1    = (const float*)d_in[2];
    const float* pm     = (const float*)d_in[3];
    const float* Wfs    = (const float*)d_in[4];
    const float* Wo1    = (const float*)d_in[5];
    const float* Wo2    = (const float*)d_in[6];
    const float* Wo3    = (const float*)d_in[7];
    const float* Wl1    = (const float*)d_in[8];
    const float* Wl2    = (const float*)d_in[9];
    const float* Wl3    = (const float*)d_in[10];

    fused_kernel<<<NT, 1024, 0, stream>>>(pm, grad, gradm1, dm1,
                                          Wfs, Wo1, Wo2, Wo3, Wl1, Wl2, Wl3,
                                          (float*)d_out);
}